// Round 1
// baseline (663.149 us; speedup 1.0000x reference)
//
#include <hip/hip_runtime.h>
#include <hip/hip_bf16.h>

#define B_SZ   2
#define T_SEQ  2048
#define C_EMB  2048
#define KV_DIM 512

typedef __bf16 bf16x8 __attribute__((ext_vector_type(8)));
typedef __bf16 bf16x4 __attribute__((ext_vector_type(4)));
typedef float  f32x4  __attribute__((ext_vector_type(4)));

// ---------------- cast f32 -> bf16 (vectorized) ----------------
__global__ __launch_bounds__(256) void cast_f32_bf16(const float* __restrict__ in,
                                                     __bf16* __restrict__ out, int n8) {
  int i = blockIdx.x * 256 + threadIdx.x;
  if (i < n8) {
    const float4* p = (const float4*)(in + (size_t)i * 8);
    float4 a = p[0], b = p[1];
    bf16x8 o;
    o[0] = (__bf16)a.x; o[1] = (__bf16)a.y; o[2] = (__bf16)a.z; o[3] = (__bf16)a.w;
    o[4] = (__bf16)b.x; o[5] = (__bf16)b.y; o[6] = (__bf16)b.z; o[7] = (__bf16)b.w;
    *(bf16x8*)(out + (size_t)i * 8) = o;
  }
}

// ---------------- transpose + cast: in[R][C] f32 -> out[C][R] bf16 ----------------
__global__ __launch_bounds__(256) void transpose_cast_kernel(const float* __restrict__ in,
                                                             __bf16* __restrict__ out,
                                                             int R, int C) {
  __shared__ float tile[64][65];
  int c0 = blockIdx.x * 64, r0 = blockIdx.y * 64;
  int tid = threadIdx.x;
#pragma unroll
  for (int i = 0; i < 4; i++) {
    int idx = tid + i * 256;          // 0..1023
    int row = idx >> 4;               // 0..63
    int c4  = (idx & 15) * 4;
    float4 v = *(const float4*)&in[(size_t)(r0 + row) * C + c0 + c4];
    tile[row][c4 + 0] = v.x; tile[row][c4 + 1] = v.y;
    tile[row][c4 + 2] = v.z; tile[row][c4 + 3] = v.w;
  }
  __syncthreads();
#pragma unroll
  for (int i = 0; i < 4; i++) {
    int idx = tid + i * 256;
    int col = idx >> 4;               // column of in = row of out
    int r4  = (idx & 15) * 4;
    bf16x4 o;
    o[0] = (__bf16)tile[r4 + 0][col];
    o[1] = (__bf16)tile[r4 + 1][col];
    o[2] = (__bf16)tile[r4 + 2][col];
    o[3] = (__bf16)tile[r4 + 3][col];
    *(bf16x4*)&out[(size_t)(c0 + col) * R + r0 + r4] = o;
  }
}

// ---------------- GEMM: C[M][N] = A[M][K] * Bt[N][K]^T + bias ----------------
// 128x128 tile, BK=32, 4 waves (2x2), mfma_f32_16x16x32_bf16.
// TRANS_OUT: write Cout[n*M + m] instead (used for V so attention reads V^T rows).
template <typename OUT_T, bool TRANS_OUT>
__global__ __launch_bounds__(256) void gemm_bt(const __bf16* __restrict__ A,
                                               const __bf16* __restrict__ Bt,
                                               const float* __restrict__ bias,
                                               OUT_T* __restrict__ Cout,
                                               int M, int N, int K) {
  __shared__ __bf16 As[128][40];   // +8 pad keeps 16B alignment, breaks bank stride
  __shared__ __bf16 Bs[128][40];
  int tid  = threadIdx.x;
  int lane = tid & 63, wave = tid >> 6;
  int wr = wave >> 1, wc = wave & 1;
  int la = lane & 15, kg = lane >> 4;
  int m0 = blockIdx.x * 128, n0 = blockIdx.y * 128;

  f32x4 acc[4][4];
#pragma unroll
  for (int i = 0; i < 4; i++)
#pragma unroll
    for (int j = 0; j < 4; j++)
#pragma unroll
      for (int r = 0; r < 4; r++) acc[i][j][r] = 0.f;

  for (int k0 = 0; k0 < K; k0 += 32) {
#pragma unroll
    for (int i = 0; i < 2; i++) {
      int s = tid + i * 256;          // 0..511
      int row = s >> 2, ko = (s & 3) * 8;
      *(bf16x8*)&As[row][ko] = *(const bf16x8*)&A[(size_t)(m0 + row) * K + k0 + ko];
      *(bf16x8*)&Bs[row][ko] = *(const bf16x8*)&Bt[(size_t)(n0 + row) * K + k0 + ko];
    }
    __syncthreads();
    bf16x8 af[4], bfr[4];
#pragma unroll
    for (int i = 0; i < 4; i++) af[i]  = *(const bf16x8*)&As[wr * 64 + i * 16 + la][kg * 8];
#pragma unroll
    for (int j = 0; j < 4; j++) bfr[j] = *(const bf16x8*)&Bs[wc * 64 + j * 16 + la][kg * 8];
#pragma unroll
    for (int i = 0; i < 4; i++)
#pragma unroll
      for (int j = 0; j < 4; j++)
        acc[i][j] = __builtin_amdgcn_mfma_f32_16x16x32_bf16(af[i], bfr[j], acc[i][j], 0, 0, 0);
    __syncthreads();
  }

#pragma unroll
  for (int i = 0; i < 4; i++) {
    int rowb = m0 + wr * 64 + i * 16 + kg * 4;
#pragma unroll
    for (int j = 0; j < 4; j++) {
      int col = n0 + wc * 64 + j * 16 + la;
      float bv = bias[col];
#pragma unroll
      for (int r = 0; r < 4; r++) {
        float v = acc[i][j][r] + bv;
        if (TRANS_OUT) Cout[(size_t)col * M + rowb + r] = (OUT_T)v;
        else           Cout[(size_t)(rowb + r) * N + col] = (OUT_T)v;
      }
    }
  }
}

// ---------------- flash GQA attention ----------------
// 1 wave per (b, h, 16-query tile). KV tiles of 32 keys.
// Q [B*T][2048] rows, K [B*T][512] rows, Vt [512][B*T] (dim-major), Y [B*T][2048].
__global__ __launch_bounds__(64) void attn_kernel(const __bf16* __restrict__ Q,
                                                  const __bf16* __restrict__ K,
                                                  const __bf16* __restrict__ Vt,
                                                  __bf16* __restrict__ Y) {
  __shared__ __bf16 Plds[16][40];   // [q row][key col], padded
  int lane = threadIdx.x;
  int la = lane & 15, kg = lane >> 4;
  int qt = blockIdx.x;              // 0..127
  int bh = blockIdx.y;              // 0..63
  int b = bh >> 5, h = bh & 31;
  int kvh = h >> 2;
  int t0 = qt * 16;

  // Q fragments: A-operand, row = la (query), k = dim
  const __bf16* qbase = Q + ((size_t)(b * T_SEQ + t0 + la)) * C_EMB + h * 64;
  bf16x8 qf0 = *(const bf16x8*)(qbase + kg * 8);
  bf16x8 qf1 = *(const bf16x8*)(qbase + 32 + kg * 8);

  f32x4 acc[4];                     // per d-tile; reg r <-> q row kg*4+r, col la <-> dim
  float mrun[4], lrun[4];
#pragma unroll
  for (int r = 0; r < 4; r++) {
    mrun[r] = -1e30f; lrun[r] = 0.f;
#pragma unroll
    for (int dt = 0; dt < 4; dt++) acc[dt][r] = 0.f;
  }

  const int nk = t0 + 16;           // keys [0, nk)
  for (int kb = 0; kb < nk; kb += 32) {
    // ---- S = Q K^T for 2 key half-tiles of 16
    f32x4 S[2];
#pragma unroll
    for (int s2 = 0; s2 < 2; s2++) {
      int krow = kb + s2 * 16 + la;
      if (krow > nk - 1) krow = nk - 1;            // clamp (masked anyway)
      const __bf16* kp = K + (size_t)(b * T_SEQ + krow) * KV_DIM + kvh * 64;
      bf16x8 kf0 = *(const bf16x8*)(kp + kg * 8);
      bf16x8 kf1 = *(const bf16x8*)(kp + 32 + kg * 8);
      f32x4 z; z[0] = z[1] = z[2] = z[3] = 0.f;
      S[s2] = __builtin_amdgcn_mfma_f32_16x16x32_bf16(qf0, kf0, z, 0, 0, 0);
      S[s2] = __builtin_amdgcn_mfma_f32_16x16x32_bf16(qf1, kf1, S[s2], 0, 0, 0);
    }
    // ---- scale + causal mask + row max
    float mloc[4];
#pragma unroll
    for (int r = 0; r < 4; r++) {
      int qrow = t0 + kg * 4 + r;
      float v0 = S[0][r] * 0.125f;
      float v1 = S[1][r] * 0.125f;
      v0 = (kb + la      <= qrow) ? v0 : -INFINITY;
      v1 = (kb + 16 + la <= qrow) ? v1 : -INFINITY;
      S[0][r] = v0; S[1][r] = v1;
      mloc[r] = fmaxf(v0, v1);
    }
#pragma unroll
    for (int off = 1; off < 16; off <<= 1)
#pragma unroll
      for (int r = 0; r < 4; r++) mloc[r] = fmaxf(mloc[r], __shfl_xor(mloc[r], off, 64));

    // ---- online softmax update, P -> LDS (bf16)
    float corr[4], psum[4];
#pragma unroll
    for (int r = 0; r < 4; r++) {
      float mnew = fmaxf(mrun[r], mloc[r]);
      corr[r] = __expf(mrun[r] - mnew);
      mrun[r] = mnew;
      float p0 = __expf(S[0][r] - mnew);
      float p1 = __expf(S[1][r] - mnew);
      psum[r] = p0 + p1;
      Plds[kg * 4 + r][la]      = (__bf16)p0;
      Plds[kg * 4 + r][16 + la] = (__bf16)p1;
    }
#pragma unroll
    for (int off = 1; off < 16; off <<= 1)
#pragma unroll
      for (int r = 0; r < 4; r++) psum[r] += __shfl_xor(psum[r], off, 64);
#pragma unroll
    for (int r = 0; r < 4; r++) {
      lrun[r] = lrun[r] * corr[r] + psum[r];
#pragma unroll
      for (int dt = 0; dt < 4; dt++) acc[dt][r] *= corr[r];
    }
    __syncthreads();

    // ---- PV: A = P[16q x 32k] from LDS, B = V^T rows (contiguous in key)
    bf16x8 pf = *(const bf16x8*)&Plds[la][kg * 8];
    int kch = kb + kg * 8;
    if (kch >= nk) kch = 0;                         // masked chunk: P=0, read anything valid
#pragma unroll
    for (int dt = 0; dt < 4; dt++) {
      const __bf16* vp = Vt + (size_t)(kvh * 64 + dt * 16 + la) * (B_SZ * T_SEQ)
                            + (size_t)b * T_SEQ + kch;
      bf16x8 vf = *(const bf16x8*)vp;
      acc[dt] = __builtin_amdgcn_mfma_f32_16x16x32_bf16(pf, vf, acc[dt], 0, 0, 0);
    }
    __syncthreads();   // protect Plds WAR for next iteration
  }

  // ---- normalize + write Y
#pragma unroll
  for (int dt = 0; dt < 4; dt++)
#pragma unroll
    for (int r = 0; r < 4; r++) {
      float y = acc[dt][r] / lrun[r];
      Y[(size_t)(b * T_SEQ + t0 + kg * 4 + r) * C_EMB + h * 64 + dt * 16 + la] = (__bf16)y;
    }
}

// ---------------- launch ----------------
extern "C" void kernel_launch(void* const* d_in, const int* in_sizes, int n_in,
                              void* d_out, int out_size, void* d_ws, size_t ws_size,
                              hipStream_t stream) {
  const float* x  = (const float*)d_in[0];
  const float* Wq = (const float*)d_in[1];
  const float* bq = (const float*)d_in[2];
  const float* Wk = (const float*)d_in[3];
  const float* bk = (const float*)d_in[4];
  const float* Wv = (const float*)d_in[5];
  const float* bv = (const float*)d_in[6];
  const float* Wo = (const float*)d_in[7];
  const float* bo = (const float*)d_in[8];
  float* out = (float*)d_out;

  const int M = B_SZ * T_SEQ;       // 4096

  char* w = (char*)d_ws;
  __bf16* xb  = (__bf16*)w; w += (size_t)M * C_EMB * 2;
  __bf16* Wqt = (__bf16*)w; w += (size_t)C_EMB * C_EMB * 2;
  __bf16* Wkt = (__bf16*)w; w += (size_t)KV_DIM * C_EMB * 2;
  __bf16* Wvt = (__bf16*)w; w += (size_t)KV_DIM * C_EMB * 2;
  __bf16* Wot = (__bf16*)w; w += (size_t)C_EMB * C_EMB * 2;
  __bf16* qb  = (__bf16*)w; w += (size_t)M * C_EMB * 2;
  __bf16* kbf = (__bf16*)w; w += (size_t)M * KV_DIM * 2;
  __bf16* vbt = (__bf16*)w; w += (size_t)KV_DIM * M * 2;
  __bf16* yb  = (__bf16*)w; w += (size_t)M * C_EMB * 2;

  cast_f32_bf16<<<(M * C_EMB / 8 + 255) / 256, 256, 0, stream>>>(x, xb, M * C_EMB / 8);

  transpose_cast_kernel<<<dim3(C_EMB / 64, C_EMB / 64), 256, 0, stream>>>(Wq, Wqt, C_EMB, C_EMB);
  transpose_cast_kernel<<<dim3(KV_DIM / 64, C_EMB / 64), 256, 0, stream>>>(Wk, Wkt, C_EMB, KV_DIM);
  transpose_cast_kernel<<<dim3(KV_DIM / 64, C_EMB / 64), 256, 0, stream>>>(Wv, Wvt, C_EMB, KV_DIM);
  transpose_cast_kernel<<<dim3(C_EMB / 64, C_EMB / 64), 256, 0, stream>>>(Wo, Wot, C_EMB, C_EMB);

  gemm_bt<__bf16, false><<<dim3(M / 128, C_EMB / 128), 256, 0, stream>>>(xb, Wqt, bq, qb, M, C_EMB, C_EMB);
  gemm_bt<__bf16, false><<<dim3(M / 128, KV_DIM / 128), 256, 0, stream>>>(xb, Wkt, bk, kbf, M, KV_DIM, C_EMB);
  gemm_bt<__bf16, true ><<<dim3(M / 128, KV_DIM / 128), 256, 0, stream>>>(xb, Wvt, bv, vbt, M, KV_DIM, C_EMB);

  attn_kernel<<<dim3(T_SEQ / 16, B_SZ * 32), 64, 0, stream>>>(qb, kbf, vbt, yb);

  gemm_bt<float, false><<<dim3(M / 128, C_EMB / 128), 256, 0, stream>>>(yb, Wot, bo, out, M, C_EMB, C_EMB);
}

// Round 2
// 426.981 us; speedup vs baseline: 1.5531x; 1.5531x over previous
//
#include <hip/hip_runtime.h>
#include <hip/hip_bf16.h>

#define B_SZ   2
#define T_SEQ  2048
#define C_EMB  2048
#define KV_DIM 512

typedef __bf16 bf16x8 __attribute__((ext_vector_type(8)));
typedef __bf16 bf16x4 __attribute__((ext_vector_type(4)));
typedef float  f32x4  __attribute__((ext_vector_type(4)));
typedef float  f32x16 __attribute__((ext_vector_type(16)));
typedef unsigned int u32;

typedef __attribute__((address_space(1))) const unsigned int gu32;
typedef __attribute__((address_space(3))) unsigned int lu32;
__device__ __forceinline__ void gload16(const void* g, void* l) {
  __builtin_amdgcn_global_load_lds((gu32*)g, (lu32*)l, 16, 0, 0);
}

// ---------------- cast f32 -> bf16 (vectorized) ----------------
__global__ __launch_bounds__(256) void cast_f32_bf16(const float* __restrict__ in,
                                                     __bf16* __restrict__ out, int n8) {
  int i = blockIdx.x * 256 + threadIdx.x;
  if (i < n8) {
    const float4* p = (const float4*)(in + (size_t)i * 8);
    float4 a = p[0], b = p[1];
    bf16x8 o;
    o[0] = (__bf16)a.x; o[1] = (__bf16)a.y; o[2] = (__bf16)a.z; o[3] = (__bf16)a.w;
    o[4] = (__bf16)b.x; o[5] = (__bf16)b.y; o[6] = (__bf16)b.z; o[7] = (__bf16)b.w;
    *(bf16x8*)(out + (size_t)i * 8) = o;
  }
}

// ---------------- transpose + cast: in[R][C] f32 -> out[C][R] bf16 ----------------
__global__ __launch_bounds__(256) void transpose_cast_kernel(const float* __restrict__ in,
                                                             __bf16* __restrict__ out,
                                                             int R, int C) {
  __shared__ float tile[64][65];
  int c0 = blockIdx.x * 64, r0 = blockIdx.y * 64;
  int tid = threadIdx.x;
#pragma unroll
  for (int i = 0; i < 4; i++) {
    int idx = tid + i * 256;
    int row = idx >> 4;
    int c4  = (idx & 15) * 4;
    float4 v = *(const float4*)&in[(size_t)(r0 + row) * C + c0 + c4];
    tile[row][c4 + 0] = v.x; tile[row][c4 + 1] = v.y;
    tile[row][c4 + 2] = v.z; tile[row][c4 + 3] = v.w;
  }
  __syncthreads();
#pragma unroll
  for (int i = 0; i < 4; i++) {
    int idx = tid + i * 256;
    int col = idx >> 4;
    int r4  = (idx & 15) * 4;
    bf16x4 o;
    o[0] = (__bf16)tile[r4 + 0][col];
    o[1] = (__bf16)tile[r4 + 1][col];
    o[2] = (__bf16)tile[r4 + 2][col];
    o[3] = (__bf16)tile[r4 + 3][col];
    *(bf16x4*)&out[(size_t)(c0 + col) * R + r0 + r4] = o;
  }
}

__global__ __launch_bounds__(256) void concat_bias(const float* __restrict__ bq,
                                                   const float* __restrict__ bk,
                                                   const float* __restrict__ bv,
                                                   float* __restrict__ bcat) {
  int i = blockIdx.x * 256 + threadIdx.x;
  if (i < 3072) {
    float v = (i < 2048) ? bq[i] : (i < 2560 ? bk[i - 2048] : bv[i - 2560]);
    bcat[i] = v;
  }
}

// ---------------- GEMM: C[M][N] = A[M][K] * Bt[N][K]^T + bias ----------------
// 128x128 tile, BK=32, 4 waves, global_load_lds staging (m97 structure).
// MODE 1: fused QKV epilogue (bf16; Q row-major, K row-major, V transposed).
// MODE 2: f32 row-major out.
template <int MODE>
__global__ __launch_bounds__(256) void gemm_bt(const __bf16* __restrict__ A,
                                               const __bf16* __restrict__ Bt,
                                               const float* __restrict__ bias,
                                               void* __restrict__ out0,
                                               __bf16* __restrict__ outK,
                                               __bf16* __restrict__ outV,
                                               int M, int N, int K) {
  __shared__ __bf16 As[128 * 32];
  __shared__ __bf16 Bs[128 * 32];
  int tid  = threadIdx.x;
  int lane = tid & 63, wave = tid >> 6;
  int wr = wave >> 1, wc = wave & 1;
  int la = lane & 15, kg = lane >> 4;
  int m0 = blockIdx.x * 128, n0 = blockIdx.y * 128;

  f32x4 acc[4][4];
#pragma unroll
  for (int i = 0; i < 4; i++)
#pragma unroll
    for (int j = 0; j < 4; j++)
#pragma unroll
      for (int r = 0; r < 4; r++) acc[i][j][r] = 0.f;

  int s0 = tid, s1 = tid + 256;
  const __bf16* ga0 = A  + (size_t)(m0 + (s0 >> 2)) * K + (s0 & 3) * 8;
  const __bf16* ga1 = A  + (size_t)(m0 + (s1 >> 2)) * K + (s1 & 3) * 8;
  const __bf16* gb0 = Bt + (size_t)(n0 + (s0 >> 2)) * K + (s0 & 3) * 8;
  const __bf16* gb1 = Bt + (size_t)(n0 + (s1 >> 2)) * K + (s1 & 3) * 8;
  __bf16* lA0 = As + (size_t)(0 * 256 + wave * 64) * 8;   // wave-uniform LDS dests
  __bf16* lA1 = As + (size_t)(1 * 256 + wave * 64) * 8;
  __bf16* lB0 = Bs + (size_t)(0 * 256 + wave * 64) * 8;
  __bf16* lB1 = Bs + (size_t)(1 * 256 + wave * 64) * 8;

  for (int k0 = 0; k0 < K; k0 += 32) {
    gload16(ga0 + k0, lA0);
    gload16(ga1 + k0, lA1);
    gload16(gb0 + k0, lB0);
    gload16(gb1 + k0, lB1);
    __syncthreads();
    bf16x8 af[4], bfr[4];
#pragma unroll
    for (int i = 0; i < 4; i++) af[i]  = *(const bf16x8*)&As[(size_t)(wr * 64 + i * 16 + la) * 32 + kg * 8];
#pragma unroll
    for (int j = 0; j < 4; j++) bfr[j] = *(const bf16x8*)&Bs[(size_t)(wc * 64 + j * 16 + la) * 32 + kg * 8];
#pragma unroll
    for (int i = 0; i < 4; i++)
#pragma unroll
      for (int j = 0; j < 4; j++)
        acc[i][j] = __builtin_amdgcn_mfma_f32_16x16x32_bf16(af[i], bfr[j], acc[i][j], 0, 0, 0);
    __syncthreads();
  }

#pragma unroll
  for (int i = 0; i < 4; i++) {
    int rowb = m0 + wr * 64 + i * 16 + kg * 4;
#pragma unroll
    for (int j = 0; j < 4; j++) {
      int col = n0 + wc * 64 + j * 16 + la;
      float bv = bias[col];
#pragma unroll
      for (int r = 0; r < 4; r++) {
        float v = acc[i][j][r] + bv;
        if (MODE == 2) {
          ((float*)out0)[(size_t)(rowb + r) * N + col] = v;
        } else {
          if (n0 < 2048)      ((__bf16*)out0)[(size_t)(rowb + r) * 2048 + col] = (__bf16)v;
          else if (n0 < 2560) outK[(size_t)(rowb + r) * 512 + (col - 2048)] = (__bf16)v;
          else                outV[(size_t)(col - 2560) * M + rowb + r] = (__bf16)v;
        }
      }
    }
  }
}

// ---------------- flash GQA attention, swapped-operand 32x32 ----------------
// 2 waves/block, 32 queries/wave. S^T = mfma(K,Q): lane owns one query column.
// PV swapped: Y^T = mfma(V^T, P^T): corr and 1/l are per-lane scalars.
__global__ __launch_bounds__(128) void attn_kernel(const __bf16* __restrict__ Q,
                                                   const __bf16* __restrict__ K,
                                                   const __bf16* __restrict__ Vt,
                                                   __bf16* __restrict__ Y) {
  __shared__ __bf16 Ylds[2][32][72];
  const int M = B_SZ * T_SEQ;
  int tid = threadIdx.x;
  int wv = tid >> 6, l = tid & 63;
  int qcol = l & 31, hh = l >> 5;
  // XCD-contiguous + heavy-diagonal-first work remap (bijective, 2048 = 8*256)
  int g = blockIdx.x;
  int w = (g & 7) * 256 + (g >> 3);
  int bh = w >> 5;
  int qt = 31 - (w & 31);
  int b = bh >> 5, hq = bh & 31, kvh = hq >> 2;
  int q0w = qt * 64 + wv * 32;

  const __bf16* qrow = Q + (size_t)(b * T_SEQ + q0w + qcol) * C_EMB + hq * 64;
  bf16x8 qf[4];
#pragma unroll
  for (int c = 0; c < 4; c++) qf[c] = *(const bf16x8*)(qrow + c * 16 + hh * 8);

  f32x16 acc0, acc1;
#pragma unroll
  for (int r = 0; r < 16; r++) { acc0[r] = 0.f; acc1[r] = 0.f; }
  float m_run = -1e30f, l_run = 0.f;
  const float SC = 0.125f * 1.44269504f;   // scale * log2(e)

  const __bf16* kbase = K + (size_t)(b * T_SEQ) * KV_DIM + kvh * 64;
  const __bf16* v0 = Vt + (size_t)(kvh * 64 + qcol) * M + (size_t)b * T_SEQ;
  const __bf16* v1 = v0 + (size_t)32 * M;

  for (int kb = 0; kb <= q0w; kb += 32) {
    // ---- S^T[32k x 32q] over d=64 (4 chained MFMAs)
    f32x16 s;
#pragma unroll
    for (int r = 0; r < 16; r++) s[r] = 0.f;
    const __bf16* krow = kbase + (size_t)(kb + qcol) * KV_DIM;
#pragma unroll
    for (int c = 0; c < 4; c++) {
      bf16x8 kf = *(const bf16x8*)(krow + c * 16 + hh * 8);
      s = __builtin_amdgcn_mfma_f32_32x32x16_bf16(kf, qf[c], s, 0, 0, 0);
    }
    // ---- causal mask (diagonal step only)
    if (kb == q0w) {
#pragma unroll
      for (int r = 0; r < 16; r++) {
        int kr = (r & 3) + 8 * (r >> 2) + 4 * hh;
        s[r] = (kr <= qcol) ? s[r] : -1e30f;
      }
    }
    // ---- row max: in-register + one cross-half shuffle
    float mloc = s[0];
#pragma unroll
    for (int r = 1; r < 16; r++) mloc = fmaxf(mloc, s[r]);
    mloc = fmaxf(mloc, __shfl_xor(mloc, 32, 64));
    // ---- deferred rescale (T13): skip unless max grew past threshold
    if (__any(mloc > m_run + 33.0f)) {
      float mnew = fmaxf(m_run, mloc);
      float corr = exp2f((m_run - mnew) * SC);
      l_run *= corr;
#pragma unroll
      for (int r = 0; r < 16; r++) { acc0[r] *= corr; acc1[r] *= corr; }
      m_run = mnew;
    }
    // ---- P = exp2((s-m)*SC), row sum in-register
    float p[16]; float ps = 0.f;
#pragma unroll
    for (int r = 0; r < 16; r++) { p[r] = exp2f((s[r] - m_run) * SC); ps += p[r]; }
    ps += __shfl_xor(ps, 32, 64);
    l_run += ps;
    // ---- pack P to bf16x2 words; redistribute across lane halves for B-fragments
    u32 P[8];
#pragma unroll
    for (int j = 0; j < 8; j++) {
      union { __bf16 b2[2]; u32 u; } pk;
      pk.b2[0] = (__bf16)p[2 * j]; pk.b2[1] = (__bf16)p[2 * j + 1];
      P[j] = pk.u;
    }
    u32 xP[8];
#pragma unroll
    for (int j = 0; j < 8; j++) xP[j] = (u32)__shfl_xor((int)P[j], 32, 64);
    union { u32 u[4]; bf16x8 v; } w0u, w1u;
    w0u.u[0] = hh ? xP[2] : P[0];
    w0u.u[1] = hh ? xP[3] : P[1];
    w0u.u[2] = hh ? P[2]  : xP[0];
    w0u.u[3] = hh ? P[3]  : xP[1];
    w1u.u[0] = hh ? xP[6] : P[4];
    w1u.u[1] = hh ? xP[7] : P[5];
    w1u.u[2] = hh ? P[6]  : xP[4];
    w1u.u[3] = hh ? P[7]  : xP[5];
    // ---- PV: Y^T += V^T * P^T  (A = Vt rows, contiguous 16B)
    const __bf16* vr0 = v0 + kb;
    const __bf16* vr1 = v1 + kb;
    bf16x8 vf00 = *(const bf16x8*)(vr0 + hh * 8);
    bf16x8 vf01 = *(const bf16x8*)(vr0 + 16 + hh * 8);
    bf16x8 vf10 = *(const bf16x8*)(vr1 + hh * 8);
    bf16x8 vf11 = *(const bf16x8*)(vr1 + 16 + hh * 8);
    acc0 = __builtin_amdgcn_mfma_f32_32x32x16_bf16(vf00, w0u.v, acc0, 0, 0, 0);
    acc0 = __builtin_amdgcn_mfma_f32_32x32x16_bf16(vf01, w1u.v, acc0, 0, 0, 0);
    acc1 = __builtin_amdgcn_mfma_f32_32x32x16_bf16(vf10, w0u.v, acc1, 0, 0, 0);
    acc1 = __builtin_amdgcn_mfma_f32_32x32x16_bf16(vf11, w1u.v, acc1, 0, 0, 0);
  }

  // ---- epilogue: normalize, LDS transpose, coalesced-ish 16B stores
  float inv = 1.0f / l_run;
  __bf16 (*slab)[72] = Ylds[wv];
#pragma unroll
  for (int r = 0; r < 16; r++) {
    int drow = (r & 3) + 8 * (r >> 2) + 4 * hh;
    slab[qcol][drow]      = (__bf16)(acc0[r] * inv);
    slab[qcol][32 + drow] = (__bf16)(acc1[r] * inv);
  }
  __syncthreads();
  __bf16* yrow = Y + (size_t)(b * T_SEQ + q0w + qcol) * C_EMB + hq * 64 + hh * 32;
#pragma unroll
  for (int c = 0; c < 4; c++)
    *(bf16x8*)(yrow + c * 8) = *(const bf16x8*)&slab[qcol][hh * 32 + c * 8];
}

// ---------------- launch ----------------
extern "C" void kernel_launch(void* const* d_in, const int* in_sizes, int n_in,
                              void* d_out, int out_size, void* d_ws, size_t ws_size,
                              hipStream_t stream) {
  const float* x  = (const float*)d_in[0];
  const float* Wq = (const float*)d_in[1];
  const float* bq = (const float*)d_in[2];
  const float* Wk = (const float*)d_in[3];
  const float* bk = (const float*)d_in[4];
  const float* Wv = (const float*)d_in[5];
  const float* bv = (const float*)d_in[6];
  const float* Wo = (const float*)d_in[7];
  const float* bo = (const float*)d_in[8];
  float* out = (float*)d_out;

  const int M = B_SZ * T_SEQ;       // 4096

  char* w = (char*)d_ws;
  __bf16* xb   = (__bf16*)w; w += (size_t)M * C_EMB * 2;
  __bf16* Wall = (__bf16*)w; w += (size_t)3072 * C_EMB * 2;   // [Wq^T; Wk^T; Wv^T]
  __bf16* Wot  = (__bf16*)w; w += (size_t)C_EMB * C_EMB * 2;
  float*  bcat = (float*)w;  w += (size_t)3072 * 4;
  __bf16* qb   = (__bf16*)w; w += (size_t)M * C_EMB * 2;
  __bf16* kbf  = (__bf16*)w; w += (size_t)M * KV_DIM * 2;
  __bf16* vbt  = (__bf16*)w; w += (size_t)KV_DIM * M * 2;
  __bf16* yb   = (__bf16*)w; w += (size_t)M * C_EMB * 2;

  cast_f32_bf16<<<(M * C_EMB / 8 + 255) / 256, 256, 0, stream>>>(x, xb, M * C_EMB / 8);

  transpose_cast_kernel<<<dim3(C_EMB / 64, C_EMB / 64), 256, 0, stream>>>(Wq, Wall, C_EMB, C_EMB);
  transpose_cast_kernel<<<dim3(KV_DIM / 64, C_EMB / 64), 256, 0, stream>>>(Wk, Wall + (size_t)2048 * C_EMB, C_EMB, KV_DIM);
  transpose_cast_kernel<<<dim3(KV_DIM / 64, C_EMB / 64), 256, 0, stream>>>(Wv, Wall + (size_t)2560 * C_EMB, C_EMB, KV_DIM);
  transpose_cast_kernel<<<dim3(C_EMB / 64, C_EMB / 64), 256, 0, stream>>>(Wo, Wot, C_EMB, C_EMB);
  concat_bias<<<12, 256, 0, stream>>>(bq, bk, bv, bcat);

  // fused QKV projection: [4096 x 3072] = xb * Wall^T
  gemm_bt<1><<<dim3(M / 128, 3072 / 128), 256, 0, stream>>>(xb, Wall, bcat, qb, kbf, vbt, M, 3072, C_EMB);

  attn_kernel<<<dim3(2048), 128, 0, stream>>>(qb, kbf, vbt, yb);

  gemm_bt<2><<<dim3(M / 128, C_EMB / 128), 256, 0, stream>>>(yb, Wot, bo, out, nullptr, nullptr, M, C_EMB, C_EMB);
}

// Round 5
// 382.207 us; speedup vs baseline: 1.7351x; 1.1171x over previous
//
#include <hip/hip_runtime.h>
#include <hip/hip_bf16.h>

#define B_SZ   2
#define T_SEQ  2048
#define C_EMB  2048
#define KV_DIM 512

typedef __bf16 bf16x8 __attribute__((ext_vector_type(8)));
typedef __bf16 bf16x4 __attribute__((ext_vector_type(4)));
typedef float  f32x4  __attribute__((ext_vector_type(4)));
typedef float  f32x16 __attribute__((ext_vector_type(16)));
typedef unsigned int u32;

typedef __attribute__((address_space(1))) const unsigned int gu32;
typedef __attribute__((address_space(3))) unsigned int lu32;
__device__ __forceinline__ void gload16(const void* g, void* l) {
  __builtin_amdgcn_global_load_lds((gu32*)g, (lu32*)l, 16, 0, 0);
}

// ---------------- cast f32 -> bf16 (vectorized) ----------------
__global__ __launch_bounds__(256) void cast_f32_bf16(const float* __restrict__ in,
                                                     __bf16* __restrict__ out, int n8) {
  int i = blockIdx.x * 256 + threadIdx.x;
  if (i < n8) {
    const float4* p = (const float4*)(in + (size_t)i * 8);
    float4 a = p[0], b = p[1];
    bf16x8 o;
    o[0] = (__bf16)a.x; o[1] = (__bf16)a.y; o[2] = (__bf16)a.z; o[3] = (__bf16)a.w;
    o[4] = (__bf16)b.x; o[5] = (__bf16)b.y; o[6] = (__bf16)b.z; o[7] = (__bf16)b.w;
    *(bf16x8*)(out + (size_t)i * 8) = o;
  }
}

// ---------------- transpose + cast: in[R][C] f32 -> out[C][R] bf16 ----------------
__global__ __launch_bounds__(256) void transpose_cast_kernel(const float* __restrict__ in,
                                                             __bf16* __restrict__ out,
                                                             int R, int C) {
  __shared__ float tile[64][65];
  int c0 = blockIdx.x * 64, r0 = blockIdx.y * 64;
  int tid = threadIdx.x;
#pragma unroll
  for (int i = 0; i < 4; i++) {
    int idx = tid + i * 256;
    int row = idx >> 4;
    int c4  = (idx & 15) * 4;
    float4 v = *(const float4*)&in[(size_t)(r0 + row) * C + c0 + c4];
    tile[row][c4 + 0] = v.x; tile[row][c4 + 1] = v.y;
    tile[row][c4 + 2] = v.z; tile[row][c4 + 3] = v.w;
  }
  __syncthreads();
#pragma unroll
  for (int i = 0; i < 4; i++) {
    int idx = tid + i * 256;
    int col = idx >> 4;
    int r4  = (idx & 15) * 4;
    bf16x4 o;
    o[0] = (__bf16)tile[r4 + 0][col];
    o[1] = (__bf16)tile[r4 + 1][col];
    o[2] = (__bf16)tile[r4 + 2][col];
    o[3] = (__bf16)tile[r4 + 3][col];
    *(bf16x4*)&out[(size_t)(c0 + col) * R + r0 + r4] = o;
  }
}

__global__ __launch_bounds__(256) void concat_bias(const float* __restrict__ bq,
                                                   const float* __restrict__ bk,
                                                   const float* __restrict__ bv,
                                                   float* __restrict__ bcat) {
  int i = blockIdx.x * 256 + threadIdx.x;
  if (i < 3072) {
    float v = (i < 2048) ? bq[i] : (i < 2560 ? bk[i - 2048] : bv[i - 2560]);
    bcat[i] = v;
  }
}

// ---------------- GEMM: C[M][N] = A[M][K] * Bt[N][K]^T + bias ----------------
// 128x128 tile, BK=32, 4 waves, global_load_lds staging (m97 structure).
// MODE 1: fused QKV epilogue (Q prescaled by 0.125*log2e, K row-major, V transposed).
// MODE 2: f32 row-major out.
template <int MODE>
__global__ __launch_bounds__(256) void gemm_bt(const __bf16* __restrict__ A,
                                               const __bf16* __restrict__ Bt,
                                               const float* __restrict__ bias,
                                               void* __restrict__ out0,
                                               __bf16* __restrict__ outK,
                                               __bf16* __restrict__ outV,
                                               int M, int N, int K) {
  __shared__ __bf16 As[128 * 32];
  __shared__ __bf16 Bs[128 * 32];
  int tid  = threadIdx.x;
  int lane = tid & 63, wave = tid >> 6;
  int wr = wave >> 1, wc = wave & 1;
  int la = lane & 15, kg = lane >> 4;
  int m0 = blockIdx.x * 128, n0 = blockIdx.y * 128;

  f32x4 acc[4][4];
#pragma unroll
  for (int i = 0; i < 4; i++)
#pragma unroll
    for (int j = 0; j < 4; j++)
#pragma unroll
      for (int r = 0; r < 4; r++) acc[i][j][r] = 0.f;

  int s0 = tid, s1 = tid + 256;
  const __bf16* ga0 = A  + (size_t)(m0 + (s0 >> 2)) * K + (s0 & 3) * 8;
  const __bf16* ga1 = A  + (size_t)(m0 + (s1 >> 2)) * K + (s1 & 3) * 8;
  const __bf16* gb0 = Bt + (size_t)(n0 + (s0 >> 2)) * K + (s0 & 3) * 8;
  const __bf16* gb1 = Bt + (size_t)(n0 + (s1 >> 2)) * K + (s1 & 3) * 8;
  __bf16* lA0 = As + (size_t)(0 * 256 + wave * 64) * 8;
  __bf16* lA1 = As + (size_t)(1 * 256 + wave * 64) * 8;
  __bf16* lB0 = Bs + (size_t)(0 * 256 + wave * 64) * 8;
  __bf16* lB1 = Bs + (size_t)(1 * 256 + wave * 64) * 8;

  for (int k0 = 0; k0 < K; k0 += 32) {
    gload16(ga0 + k0, lA0);
    gload16(ga1 + k0, lA1);
    gload16(gb0 + k0, lB0);
    gload16(gb1 + k0, lB1);
    __syncthreads();
    bf16x8 af[4], bfr[4];
#pragma unroll
    for (int i = 0; i < 4; i++) af[i]  = *(const bf16x8*)&As[(size_t)(wr * 64 + i * 16 + la) * 32 + kg * 8];
#pragma unroll
    for (int j = 0; j < 4; j++) bfr[j] = *(const bf16x8*)&Bs[(size_t)(wc * 64 + j * 16 + la) * 32 + kg * 8];
#pragma unroll
    for (int i = 0; i < 4; i++)
#pragma unroll
      for (int j = 0; j < 4; j++)
        acc[i][j] = __builtin_amdgcn_mfma_f32_16x16x32_bf16(af[i], bfr[j], acc[i][j], 0, 0, 0);
    __syncthreads();
  }

#pragma unroll
  for (int i = 0; i < 4; i++) {
    int rowb = m0 + wr * 64 + i * 16 + kg * 4;
#pragma unroll
    for (int j = 0; j < 4; j++) {
      int col = n0 + wc * 64 + j * 16 + la;
      float bv = bias[col];
#pragma unroll
      for (int r = 0; r < 4; r++) {
        float v = acc[i][j][r] + bv;
        if (MODE == 2) {
          ((float*)out0)[(size_t)(rowb + r) * N + col] = v;
        } else {
          if (n0 < 2048)      ((__bf16*)out0)[(size_t)(rowb + r) * 2048 + col] = (__bf16)(v * 0.18033688f);
          else if (n0 < 2560) outK[(size_t)(rowb + r) * 512 + (col - 2048)] = (__bf16)v;
          else                outV[(size_t)(col - 2560) * M + rowb + r] = (__bf16)v;
        }
      }
    }
  }
}

// ---------------- flash GQA attention, swapped-operand 32x32 ----------------
// 2 waves/block, 32 queries/wave. S^T = mfma(K,Q) (Q prescaled by 0.125*log2e).
// PV swapped: Y^T = mfma(V^T, P^T). K prefetched one tile ahead.
// Cross-half traffic via __shfl_xor(32) (verified in round 2).
__global__ __launch_bounds__(128) void attn_kernel(const __bf16* __restrict__ Q,
                                                   const __bf16* __restrict__ K,
                                                   const __bf16* __restrict__ Vt,
                                                   __bf16* __restrict__ Y) {
  __shared__ __bf16 Ylds[2][32][72];
  const int M = B_SZ * T_SEQ;
  int tid = threadIdx.x;
  int wv = tid >> 6, l = tid & 63;
  int qcol = l & 31, hh = l >> 5;
  int g = blockIdx.x;
  int qt = 31 - (g >> 6);           // heavy-first (LPT) dispatch order
  int bh = g & 63;
  int b = bh >> 5, hq = bh & 31, kvh = hq >> 2;
  int q0w = qt * 64 + wv * 32;

  const __bf16* qrow = Q + (size_t)(b * T_SEQ + q0w + qcol) * C_EMB + hq * 64;
  bf16x8 qf[4];
#pragma unroll
  for (int c = 0; c < 4; c++) qf[c] = *(const bf16x8*)(qrow + c * 16 + hh * 8);

  f32x16 acc0, acc1;
#pragma unroll
  for (int r = 0; r < 16; r++) { acc0[r] = 0.f; acc1[r] = 0.f; }
  float m_run = -1e30f, l_run = 0.f;

  const __bf16* kbase = K + (size_t)(b * T_SEQ + qcol) * KV_DIM + kvh * 64 + hh * 8;
  const __bf16* vb0 = Vt + (size_t)(kvh * 64 + qcol) * M + (size_t)b * T_SEQ + hh * 8;
  const __bf16* vb1 = vb0 + (size_t)32 * M;

  bf16x8 kf[4];
#pragma unroll
  for (int c = 0; c < 4; c++) kf[c] = *(const bf16x8*)(kbase + c * 16);

  for (int kb = 0; kb <= q0w; kb += 32) {
    // ---- S^T[32k x 32q] over d=64
    f32x16 s;
#pragma unroll
    for (int r = 0; r < 16; r++) s[r] = 0.f;
    __builtin_amdgcn_s_setprio(1);
#pragma unroll
    for (int c = 0; c < 4; c++)
      s = __builtin_amdgcn_mfma_f32_32x32x16_bf16(kf[c], qf[c], s, 0, 0, 0);
    __builtin_amdgcn_s_setprio(0);
    // ---- prefetch next K tile (clamped; wasted only on last iter)
    {
      int nkb = (kb + 32 <= q0w) ? kb + 32 : 0;
      const __bf16* nk = kbase + (size_t)nkb * KV_DIM;
#pragma unroll
      for (int c = 0; c < 4; c++) kf[c] = *(const bf16x8*)(nk + c * 16);
    }
    // ---- V loads (independent; compiler hoists above softmax)
    bf16x8 vf0 = *(const bf16x8*)(vb0 + kb);
    bf16x8 vf1 = *(const bf16x8*)(vb0 + kb + 16);
    bf16x8 vf2 = *(const bf16x8*)(vb1 + kb);
    bf16x8 vf3 = *(const bf16x8*)(vb1 + kb + 16);
    // ---- causal mask (diagonal tile only)
    if (kb == q0w) {
#pragma unroll
      for (int r = 0; r < 16; r++) {
        int kr = (r & 3) + 8 * (r >> 2) + 4 * hh;
        s[r] = (kr <= qcol) ? s[r] : -1e30f;
      }
    }
    // ---- row max: in-register tree + one cross-half shuffle
    float m01 = fmaxf(s[0], s[1]),  m23 = fmaxf(s[2], s[3]);
    float m45 = fmaxf(s[4], s[5]),  m67 = fmaxf(s[6], s[7]);
    float m89 = fmaxf(s[8], s[9]),  mab = fmaxf(s[10], s[11]);
    float mcd = fmaxf(s[12], s[13]), mef = fmaxf(s[14], s[15]);
    float mloc = fmaxf(fmaxf(fmaxf(m01, m23), fmaxf(m45, m67)),
                       fmaxf(fmaxf(m89, mab), fmaxf(mcd, mef)));
    mloc = fmaxf(mloc, __shfl_xor(mloc, 32, 64));
    // ---- deferred rescale (log2 domain; p <= 2^6, r2-equivalent threshold)
    if (__any(mloc > m_run + 6.0f)) {
      float mnew = fmaxf(m_run, mloc);
      float corr = exp2f(m_run - mnew);
      l_run *= corr;
#pragma unroll
      for (int r = 0; r < 16; r++) { acc0[r] *= corr; acc1[r] *= corr; }
      m_run = mnew;
    }
    // ---- P = exp2(s - m) in place; per-lane partial row sum (finished in epilogue)
    float ps = 0.f;
#pragma unroll
    for (int r = 0; r < 16; r++) { s[r] = exp2f(s[r] - m_run); ps += s[r]; }
    l_run += ps;
    // ---- pack to bf16 pairs; shfl_xor(32) + select builds both B-fragments (r2-verified)
    u32 P[8];
#pragma unroll
    for (int j = 0; j < 8; j++) {
      union { __bf16 b2[2]; u32 u; } pk;
      pk.b2[0] = (__bf16)s[2 * j]; pk.b2[1] = (__bf16)s[2 * j + 1];
      P[j] = pk.u;
    }
    u32 xP[8];
#pragma unroll
    for (int j = 0; j < 8; j++) xP[j] = (u32)__shfl_xor((int)P[j], 32, 64);
    union { u32 u[4]; bf16x8 v; } w0u, w1u;
    w0u.u[0] = hh ? xP[2] : P[0];
    w0u.u[1] = hh ? xP[3] : P[1];
    w0u.u[2] = hh ? P[2]  : xP[0];
    w0u.u[3] = hh ? P[3]  : xP[1];
    w1u.u[0] = hh ? xP[6] : P[4];
    w1u.u[1] = hh ? xP[7] : P[5];
    w1u.u[2] = hh ? P[6]  : xP[4];
    w1u.u[3] = hh ? P[7]  : xP[5];
    // ---- PV: Y^T += V^T * P^T
    __builtin_amdgcn_s_setprio(1);
    acc0 = __builtin_amdgcn_mfma_f32_32x32x16_bf16(vf0, w0u.v, acc0, 0, 0, 0);
    acc0 = __builtin_amdgcn_mfma_f32_32x32x16_bf16(vf1, w1u.v, acc0, 0, 0, 0);
    acc1 = __builtin_amdgcn_mfma_f32_32x32x16_bf16(vf2, w0u.v, acc1, 0, 0, 0);
    acc1 = __builtin_amdgcn_mfma_f32_32x32x16_bf16(vf3, w1u.v, acc1, 0, 0, 0);
    __builtin_amdgcn_s_setprio(0);
  }

  // ---- finish row sum across halves, normalize, LDS transpose, 16B stores
  l_run += __shfl_xor(l_run, 32, 64);
  float inv = 1.0f / l_run;
  __bf16 (*slab)[72] = Ylds[wv];
#pragma unroll
  for (int r = 0; r < 16; r++) {
    int drow = (r & 3) + 8 * (r >> 2) + 4 * hh;
    slab[qcol][drow]      = (__bf16)(acc0[r] * inv);
    slab[qcol][32 + drow] = (__bf16)(acc1[r] * inv);
  }
  __syncthreads();
  __bf16* yrow = Y + (size_t)(b * T_SEQ + q0w + qcol) * C_EMB + hq * 64 + hh * 32;
#pragma unroll
  for (int c = 0; c < 4; c++)
    *(bf16x8*)(yrow + c * 8) = *(const bf16x8*)&slab[qcol][hh * 32 + c * 8];
}

// ---------------- launch ----------------
extern "C" void kernel_launch(void* const* d_in, const int* in_sizes, int n_in,
                              void* d_out, int out_size, void* d_ws, size_t ws_size,
                              hipStream_t stream) {
  const float* x  = (const float*)d_in[0];
  const float* Wq = (const float*)d_in[1];
  const float* bq = (const float*)d_in[2];
  const float* Wk = (const float*)d_in[3];
  const float* bk = (const float*)d_in[4];
  const float* Wv = (const float*)d_in[5];
  const float* bv = (const float*)d_in[6];
  const float* Wo = (const float*)d_in[7];
  const float* bo = (const float*)d_in[8];
  float* out = (float*)d_out;

  const int M = B_SZ * T_SEQ;       // 4096

  char* w = (char*)d_ws;
  __bf16* xb   = (__bf16*)w; w += (size_t)M * C_EMB * 2;
  __bf16* Wall = (__bf16*)w; w += (size_t)3072 * C_EMB * 2;   // [Wq^T; Wk^T; Wv^T]
  __bf16* Wot  = (__bf16*)w; w += (size_t)C_EMB * C_EMB * 2;
  float*  bcat = (float*)w;  w += (size_t)3072 * 4;
  __bf16* qb   = (__bf16*)w; w += (size_t)M * C_EMB * 2;
  __bf16* kbf  = (__bf16*)w; w += (size_t)M * KV_DIM * 2;
  __bf16* vbt  = (__bf16*)w; w += (size_t)KV_DIM * M * 2;
  __bf16* yb   = (__bf16*)w; w += (size_t)M * C_EMB * 2;

  cast_f32_bf16<<<(M * C_EMB / 8 + 255) / 256, 256, 0, stream>>>(x, xb, M * C_EMB / 8);

  transpose_cast_kernel<<<dim3(C_EMB / 64, C_EMB / 64), 256, 0, stream>>>(Wq, Wall, C_EMB, C_EMB);
  transpose_cast_kernel<<<dim3(KV_DIM / 64, C_EMB / 64), 256, 0, stream>>>(Wk, Wall + (size_t)2048 * C_EMB, C_EMB, KV_DIM);
  transpose_cast_kernel<<<dim3(KV_DIM / 64, C_EMB / 64), 256, 0, stream>>>(Wv, Wall + (size_t)2560 * C_EMB, C_EMB, KV_DIM);
  transpose_cast_kernel<<<dim3(C_EMB / 64, C_EMB / 64), 256, 0, stream>>>(Wo, Wot, C_EMB, C_EMB);
  concat_bias<<<12, 256, 0, stream>>>(bq, bk, bv, bcat);

  // fused QKV projection: [4096 x 3072] = xb * Wall^T
  gemm_bt<1><<<dim3(M / 128, 3072 / 128), 256, 0, stream>>>(xb, Wall, bcat, qb, kbf, vbt, M, 3072, C_EMB);

  attn_kernel<<<dim3(2048), 128, 0, stream>>>(qb, kbf, vbt, yb);

  gemm_bt<2><<<dim3(M / 128, C_EMB / 128), 256, 0, stream>>>(yb, Wot, bo, out, nullptr, nullptr, M, C_EMB, C_EMB);
}